// Round 3
// baseline (205.672 us; speedup 1.0000x reference)
//
#include <hip/hip_runtime.h>
#include <cmath>

#define N_NODES 50000
#define N_EDGES 800000
#define N_FEAT 128
#define DIM 64
#define N_GRAPHS 512
#define GGRID ((N_NODES + 63) / 64)         // 782 gemm1 tiles
#define BH_BLK 128                          // edge-pass blocks (hist/scatter)
#define EPB (N_EDGES / BH_BLK)              // 6250 edges per edge-pass block
#define NND_PAD 50176                       // padded node count (98*512)
#define P2_NBLK (NND_PAD / 512)             // 98 scan blocks (512 elems each)

typedef short short8 __attribute__((ext_vector_type(8)));
typedef float floatx4 __attribute__((ext_vector_type(4)));

// bf16 storage helpers (RNE). Storage-only: all math in fp32.
__device__ __forceinline__ unsigned short f2bf(float f) {
  union { float f; unsigned int u; } v; v.f = f;
  return (unsigned short)((v.u + 0x7FFFu + ((v.u >> 16) & 1u)) >> 16);
}
__device__ __forceinline__ float bf2f(unsigned short u) {
  union { unsigned int u; float f; } v; v.u = (unsigned int)u << 16;
  return v.f;
}

// ---------------------------------------------------------------------------
// dispatch 1: blocks [0,128) node-level in-degree histogram (global atomics,
// indeg pre-zeroed by memset); block 128 = w2fc = W2@Wfc; block 129 = W1
// split into bf16 head+residual, transposed [c][k] for the zero-LDS gemm.
__global__ __launch_bounds__(256) void bhist_w2fc(const int* __restrict__ dst,
                                                  int* __restrict__ indeg,
                                                  const float* __restrict__ W2,
                                                  const float* __restrict__ Wfc,
                                                  float* __restrict__ w2fc,
                                                  const float* __restrict__ W1,
                                                  unsigned short* __restrict__ w1sh,
                                                  unsigned short* __restrict__ w1sl) {
  if (blockIdx.x == BH_BLK) {
    int k = threadIdx.x;
    if (k < 64) {
      float s = 0.f;
#pragma unroll 8
      for (int j = 0; j < 64; j++) s += W2[k * 64 + j] * Wfc[j];
      w2fc[k] = s;
    }
    return;
  }
  if (blockIdx.x == BH_BLK + 1) {
    // W1 [128 k][64 c] fp32 -> w1sh/w1sl [64 c][128 k] bf16 head/residual.
    int tid = threadIdx.x;
#pragma unroll
    for (int i = 0; i < 32; i++) {
      int idx = i * 256 + tid;            // idx = c*128 + kk
      int kk = idx & 127, c = idx >> 7;
      float f = W1[kk * 64 + c];
      unsigned short h = f2bf(f);
      unsigned short l = f2bf(f - bf2f(h));
      w1sh[idx] = h;
      w1sl[idx] = l;
    }
    return;
  }
  const int tid = threadIdx.x, k = blockIdx.x;
  const int base = k * EPB;
  for (int j = tid; j < EPB; j += 256)
    atomicAdd(&indeg[dst[base + j]], 1);
}

// ---------------------------------------------------------------------------
// dispatch 2: per-512-chunk RAW sums of indeg (98 blocks, pair-indexed).
__global__ __launch_bounds__(256) void f_psum(const int* __restrict__ indeg,
                                              int* __restrict__ partials) {
  __shared__ int ws[4];
  const int tid = threadIdx.x;
  const int2* c2 = (const int2*)indeg;
  int idx = blockIdx.x * 256 + tid;                 // pair index
  int v = 0;
  if (idx * 2 < NND_PAD) { int2 c = c2[idx]; v = c.x + c.y; }
#pragma unroll
  for (int off = 32; off; off >>= 1) v += __shfl_down(v, off, 64);
  int lane = tid & 63, w = tid >> 6;
  if (lane == 0) ws[w] = v;
  __syncthreads();
  if (tid == 0) partials[blockIdx.x] = ws[0] + ws[1] + ws[2] + ws[3];
}

// ---------------------------------------------------------------------------
// dispatch 3: block-local scan of 512 indeg elems + redundant LDS scan of
// the 98 raw partials -> exclusive node offsets into rp (immutable) and rc
// (mutable scatter cursors).
__global__ __launch_bounds__(256) void f_sblocks(const int* __restrict__ indeg,
                                                 const int* __restrict__ partials,
                                                 int* __restrict__ rp,
                                                 int* __restrict__ rc) {
  __shared__ int buf[256];
  __shared__ int pbuf[256];
  const int tid = threadIdx.x;
  const int2* c2 = (const int2*)indeg;
  const int idx = blockIdx.x * 256 + tid;
  int2 c = make_int2(0, 0);
  if (idx * 2 < NND_PAD) c = c2[idx];
  int s = c.x + c.y;
  buf[tid] = s;
  pbuf[tid] = (tid < P2_NBLK) ? partials[tid] : 0;
  __syncthreads();
  for (int off = 1; off < 256; off <<= 1) {         // inclusive scans
    int t1 = (tid >= off) ? buf[tid - off] : 0;
    int t2 = (tid >= off) ? pbuf[tid - off] : 0;
    __syncthreads();
    buf[tid] += t1;
    pbuf[tid] += t2;
    __syncthreads();
  }
  const int thr_excl = buf[tid] - s;
  const int base = (blockIdx.x > 0) ? pbuf[blockIdx.x - 1] : 0;
  if (idx * 2 < NND_PAD) {
    int e0 = base + thr_excl;
    int2 o = make_int2(e0, e0 + c.x);               // exclusive offsets
    ((int2*)rp)[idx] = o;
    ((int2*)rc)[idx] = o;
  }
}

// ---------------------------------------------------------------------------
// Split-bf16 MFMA gemm1, zero-LDS: h1[64x64] = x[64x128] @ W1[128x64].
// acc = xh@Wh + xh@Wl + xl@Wh (xl@Wl ~2^-17 dropped) -> fp32-equivalent.
// C/D layout (m89-verified): col = lane&15, row = 4*(lane>>4) + reg.
__device__ __forceinline__ void gemm1_mfma(const float* __restrict__ x,
                                           const unsigned short* __restrict__ w1sh,
                                           const unsigned short* __restrict__ w1sl,
                                           unsigned short* __restrict__ h1,
                                           int row0, int tid) {
  const int lane = tid & 63, w = tid >> 6;
  const int g = lane >> 4, c15 = lane & 15;
  const int ra = row0 + (w << 4) + c15;   // this lane's A row
  const bool va = ra < N_NODES;
  const float* xr = &x[(size_t)(va ? ra : 0) * N_FEAT];
  floatx4 acc[4];
#pragma unroll
  for (int i = 0; i < 4; i++) acc[i] = (floatx4){0.f, 0.f, 0.f, 0.f};

#pragma unroll
  for (int kb = 0; kb < 128; kb += 32) {
    const int ka = kb + g * 8;            // consistent k-slice for A and B
    float4 v0 = make_float4(0.f, 0.f, 0.f, 0.f), v1 = v0;
    if (va) {
      v0 = *(const float4*)&xr[ka];
      v1 = *(const float4*)&xr[ka + 4];
    }
    const float fv[8] = {v0.x, v0.y, v0.z, v0.w, v1.x, v1.y, v1.z, v1.w};
    short8 ah, al;
#pragma unroll
    for (int j = 0; j < 8; j++) {
      unsigned short h = f2bf(fv[j]);
      ah[j] = (short)h;
      al[j] = (short)f2bf(fv[j] - bf2f(h));
    }
#pragma unroll
    for (int ct = 0; ct < 4; ct++) {
      const int cb = ct * 16 + c15;       // B column; same ka slice
      short8 bh = *(const short8*)&w1sh[cb * 128 + ka];
      short8 bl = *(const short8*)&w1sl[cb * 128 + ka];
      acc[ct] = __builtin_amdgcn_mfma_f32_16x16x32_bf16(ah, bh, acc[ct], 0, 0, 0);
      acc[ct] = __builtin_amdgcn_mfma_f32_16x16x32_bf16(ah, bl, acc[ct], 0, 0, 0);
      acc[ct] = __builtin_amdgcn_mfma_f32_16x16x32_bf16(al, bh, acc[ct], 0, 0, 0);
    }
  }

  // epilogue: col = ct*16 + c15, row = w*16 + g*4 + r
#pragma unroll
  for (int ct = 0; ct < 4; ct++) {
#pragma unroll
    for (int r = 0; r < 4; r++) {
      int gr = row0 + (w << 4) + (g << 2) + r;
      if (gr < N_NODES) h1[(size_t)gr * 64 + ct * 16 + c15] = f2bf(acc[ct][r]);
    }
  }
}

// ---------------------------------------------------------------------------
// dispatch 4: blocks [0,BH_BLK) = CSR scatter (ebuf[rc[dst]++] = src, fully
// dst-sorted); blocks [BH_BLK..) = gemm1. Scatter hides under gemm1.
__global__ __launch_bounds__(256) void gemm1_bscatter(
    const float* __restrict__ x,
    const unsigned short* __restrict__ w1sh,
    const unsigned short* __restrict__ w1sl,
    unsigned short* __restrict__ h1, const int* __restrict__ src,
    const int* __restrict__ dst, int* __restrict__ rc,
    unsigned int* __restrict__ ebuf) {
  const int tid = threadIdx.x;
  if (blockIdx.x >= BH_BLK) {
    gemm1_mfma(x, w1sh, w1sl, h1, (blockIdx.x - BH_BLK) * 64, tid);
  } else {
    const int base = blockIdx.x * EPB;
    for (int j = tid; j < EPB; j += 256) {
      int e = base + j;
      int d = dst[e];
      int pos = atomicAdd(&rc[d], 1);
      ebuf[pos] = (unsigned int)src[e];
    }
  }
}

// ---------------------------------------------------------------------------
// dispatch 5: layer-1 gather + relu + dot(w2fc) -> z[node], straight off the
// node CSR (no LDS sort). 782 blocks x 1024 threads (16 waves x 4 nodes).
__global__ __launch_bounds__(1024, 8) void gather_z_fused(
    const unsigned short* __restrict__ h1,
    const unsigned int* __restrict__ ebuf,
    const int* __restrict__ rp,
    const float* __restrict__ w2fc,
    float* __restrict__ z) {
  __shared__ int srp[65];
  __shared__ float sw[64];
  const int tid = threadIdx.x;
  const int b = blockIdx.x;
  if (tid < 65) srp[tid] = rp[b * 64 + tid];
  if (tid < 64) sw[tid] = w2fc[tid];
  __syncthreads();

  const int lane = tid & 63, w = tid >> 6;
  const int eo = lane >> 4, qfo = (lane & 15) << 2;
#pragma unroll
  for (int ni = 0; ni < 4; ni++) {
    const int r = ni * 16 + w;
    const int i1 = srp[r + 1];
    int i = srp[r];
    float4 acc = make_float4(0.f, 0.f, 0.f, 0.f);
    for (; i + 16 <= i1; i += 16) {
      int s0 = ebuf[i + eo];
      int s1 = ebuf[i + 4 + eo];
      int s2 = ebuf[i + 8 + eo];
      int s3 = ebuf[i + 12 + eo];
      ushort4 u0 = *(const ushort4*)&h1[(size_t)s0 * 64 + qfo];
      ushort4 u1 = *(const ushort4*)&h1[(size_t)s1 * 64 + qfo];
      ushort4 u2 = *(const ushort4*)&h1[(size_t)s2 * 64 + qfo];
      ushort4 u3 = *(const ushort4*)&h1[(size_t)s3 * 64 + qfo];
      acc.x += (bf2f(u0.x) + bf2f(u1.x)) + (bf2f(u2.x) + bf2f(u3.x));
      acc.y += (bf2f(u0.y) + bf2f(u1.y)) + (bf2f(u2.y) + bf2f(u3.y));
      acc.z += (bf2f(u0.z) + bf2f(u1.z)) + (bf2f(u2.z) + bf2f(u3.z));
      acc.w += (bf2f(u0.w) + bf2f(u1.w)) + (bf2f(u2.w) + bf2f(u3.w));
    }
    for (; i + 4 <= i1; i += 4) {
      int s = ebuf[i + eo];
      ushort4 u = *(const ushort4*)&h1[(size_t)s * 64 + qfo];
      acc.x += bf2f(u.x); acc.y += bf2f(u.y);
      acc.z += bf2f(u.z); acc.w += bf2f(u.w);
    }
    if (eo < i1 - i) {
      int s = ebuf[i + eo];
      ushort4 u = *(const ushort4*)&h1[(size_t)s * 64 + qfo];
      acc.x += bf2f(u.x); acc.y += bf2f(u.y);
      acc.z += bf2f(u.z); acc.w += bf2f(u.w);
    }
#pragma unroll
    for (int m = 16; m <= 32; m <<= 1) {            // reduce over eo
      acc.x += __shfl_xor(acc.x, m, 64);
      acc.y += __shfl_xor(acc.y, m, 64);
      acc.z += __shfl_xor(acc.z, m, 64);
      acc.w += __shfl_xor(acc.w, m, 64);
    }
    float p = fmaxf(acc.x, 0.f) * sw[qfo] + fmaxf(acc.y, 0.f) * sw[qfo + 1] +
              fmaxf(acc.z, 0.f) * sw[qfo + 2] + fmaxf(acc.w, 0.f) * sw[qfo + 3];
#pragma unroll
    for (int m = 1; m <= 8; m <<= 1) p += __shfl_xor(p, m, 64);
    int node = b * 64 + r;
    if (lane == 0 && node < N_NODES) z[node] = p;
  }
}

// ---------------------------------------------------------------------------
// dispatch 6: per-graph sum of z[src] over the graph's CONTIGUOUS edge range
// rp[start]..rp[end] (dst-sorted CSR); /count; sigmoid.
__global__ __launch_bounds__(256) void graph_pool(const float* __restrict__ z,
                                                  const unsigned int* __restrict__ ebuf,
                                                  const int* __restrict__ rp,
                                                  const int* __restrict__ batch,
                                                  float* __restrict__ out) {
  __shared__ float sacc[4];
  int g = blockIdx.x;
  int tid = threadIdx.x, lane = tid & 63, w = tid >> 6;

  int lo = 0, hi = N_NODES;
  while (lo < hi) { int mid = (lo + hi) >> 1; if (batch[mid] < g) lo = mid + 1; else hi = mid; }
  const int start = lo;
  hi = N_NODES;
  while (lo < hi) { int mid = (lo + hi) >> 1; if (batch[mid] < g + 1) lo = mid + 1; else hi = mid; }
  const int end = lo;

  const int e0 = rp[start], e1 = rp[end];
  float s = 0.f;
  for (int i = e0 + tid; i < e1; i += 256) s += z[ebuf[i]];
#pragma unroll
  for (int off = 32; off; off >>= 1) s += __shfl_down(s, off, 64);
  if (lane == 0) sacc[w] = s;
  __syncthreads();
  if (tid == 0) {
    float v = sacc[0] + sacc[1] + sacc[2] + sacc[3];
    v /= fmaxf((float)(end - start), 1.f);
    out[g] = 1.f / (1.f + expf(-v));
  }
}

// ---------------------------------------------------------------------------
extern "C" void kernel_launch(void* const* d_in, const int* in_sizes, int n_in,
                              void* d_out, int out_size, void* d_ws, size_t ws_size,
                              hipStream_t stream) {
  const float* x     = (const float*)d_in[0];
  const int*   ei    = (const int*)d_in[1];   // [2, E]: src then dst
  const int*   batch = (const int*)d_in[2];
  const float* W1    = (const float*)d_in[3];
  const float* W2    = (const float*)d_in[4];
  const float* Wfc   = (const float*)d_in[5];
  float*       out   = (float*)d_out;

  const int* src = ei;
  const int* dst = ei + N_EDGES;

  // workspace layout (~10.6 MB, all disjoint, 16B-aligned sections)
  char* ws = (char*)d_ws;
  unsigned short* h1 = (unsigned short*)(ws);                  // [N,64] bf16
  unsigned short* w1sh = (unsigned short*)(ws + (size_t)N_NODES * DIM * 2);  // [64][128]
  unsigned short* w1sl = w1sh + N_FEAT * DIM;                  // [64][128]
  float* z    = (float*)(w1sl + N_FEAT * DIM);                 // [N]
  float* w2fc = z + N_NODES;                                   // [64]
  int*   indeg = (int*)(w2fc + 64);                            // [NND_PAD]
  int*   rp    = indeg + NND_PAD;                              // [NND_PAD]
  int*   rc    = rp + NND_PAD;                                 // [NND_PAD]
  int*   partials = rc + NND_PAD;                              // [128] (98 used)
  unsigned int* ebuf = (unsigned int*)(partials + 128);        // [E]

  // node-level CSR front half: zero indeg -> histogram (+w2fc, +W1 split)
  // -> raw sums -> fused scan (rp immutable, rc scatter cursors)
  hipMemsetAsync(indeg, 0, NND_PAD * sizeof(int), stream);
  bhist_w2fc<<<BH_BLK + 2, 256, 0, stream>>>(dst, indeg, W2, Wfc, w2fc,
                                             W1, w1sh, w1sl);
  f_psum<<<P2_NBLK, 256, 0, stream>>>(indeg, partials);
  f_sblocks<<<P2_NBLK, 256, 0, stream>>>(indeg, partials, rp, rc);

  // CSR scatter (blocks 0..127) || gemm1 (h1 = bf16(x@W1), zero-LDS MFMA)
  gemm1_bscatter<<<GGRID + BH_BLK, 256, 0, stream>>>(x, w1sh, w1sl, h1, src,
                                                     dst, rc, ebuf);

  // layer-1 gather + relu + dot(W2@Wfc) -> z[N]  (no per-block sort)
  gather_z_fused<<<GGRID, 1024, 0, stream>>>(h1, ebuf, rp, w2fc, z);

  // per-graph contiguous edge-sum of z[src], mean, sigmoid
  graph_pool<<<N_GRAPHS, 256, 0, stream>>>(z, ebuf, rp, batch, out);
}

// Round 4
// 198.202 us; speedup vs baseline: 1.0377x; 1.0377x over previous
//
#include <hip/hip_runtime.h>
#include <cmath>

#define N_NODES 50000
#define N_EDGES 800000
#define N_FEAT 128
#define DIM 64
#define N_GRAPHS 512
#define GGRID ((N_NODES + 63) / 64)         // 782 gemm1 tiles / buckets
#define NBKT GGRID                          // bucket = dst>>6
#define BH_BLK 128                          // bucket-sort blocks
#define EPB (N_EDGES / BH_BLK)              // 6250 edges per sort block
#define NCNT (NBKT * BH_BLK)                // 100096 count-matrix entries
#define P2_NBLK ((NCNT + 511) / 512)        // 196 scan blocks (512 elems each)
#define BKT_CAP 2048                        // max bucket edges (mean 1024)

// bf16 storage helpers (RNE). Storage-only: all math in fp32.
__device__ __forceinline__ unsigned short f2bf(float f) {
  union { float f; unsigned int u; } v; v.f = f;
  return (unsigned short)((v.u + 0x7FFFu + ((v.u >> 16) & 1u)) >> 16);
}
__device__ __forceinline__ float bf2f(unsigned short u) {
  union { unsigned int u; float f; } v; v.u = (unsigned int)u << 16;
  return v.f;
}

// ---------------------------------------------------------------------------
// dispatch 1: blocks [0,128) bucket histogram of dst>>6 (cnt bucket-major:
// cnt[b*BH_BLK + k]); block 128 = w2fc = W2@Wfc precompute.
__global__ __launch_bounds__(256) void bhist_w2fc(const int* __restrict__ dst,
                                                  int* __restrict__ cnt,
                                                  const float* __restrict__ W2,
                                                  const float* __restrict__ Wfc,
                                                  float* __restrict__ w2fc) {
  if (blockIdx.x == BH_BLK) {
    int k = threadIdx.x;
    if (k < 64) {
      float s = 0.f;
#pragma unroll 8
      for (int j = 0; j < 64; j++) s += W2[k * 64 + j] * Wfc[j];
      w2fc[k] = s;
    }
    return;
  }
  __shared__ int lh[NBKT];
  const int tid = threadIdx.x, k = blockIdx.x;
  for (int i = tid; i < NBKT; i += 256) lh[i] = 0;
  __syncthreads();
  const int base = k * EPB;
  for (int j = tid; j < EPB; j += 256)
    atomicAdd(&lh[dst[base + j] >> 6], 1);
  __syncthreads();
  for (int i = tid; i < NBKT; i += 256) cnt[i * BH_BLK + k] = lh[i];
}

// ---------------------------------------------------------------------------
// dispatch 2 (fused former psum+sblocks): each block redundantly sums the
// raw cnt prefix [0, b*512) (L2-hot, ~39MB aggregate) for its base, then
// scans its own 512-chunk. Writes offsets to coff (cnt stays raw -> no
// read/write race between blocks) + bucket_ptr.
__global__ __launch_bounds__(256) void f_scan(const int* __restrict__ cnt,
                                              int* __restrict__ coff,
                                              int* __restrict__ bucket_ptr) {
  __shared__ int buf[256];
  __shared__ int ws[4];
  __shared__ int sbase;
  const int tid = threadIdx.x;
  const int b = blockIdx.x;
  // base = sum of raw cnt[0 .. b*512)
  int v = 0;
  const int pre = b * 512;
  for (int i = tid; i < pre; i += 256) v += cnt[i];
#pragma unroll
  for (int off = 32; off; off >>= 1) v += __shfl_down(v, off, 64);
  const int lane = tid & 63, w = tid >> 6;
  if (lane == 0) ws[w] = v;
  __syncthreads();
  if (tid == 0) sbase = ws[0] + ws[1] + ws[2] + ws[3];
  // chunk-local inclusive scan over 512 elems (pair-indexed)
  const int2* cnt2 = (const int2*)cnt;
  const int idx = b * 256 + tid;
  int2 c = make_int2(0, 0);
  if (idx * 2 < NCNT) c = cnt2[idx];
  int s = c.x + c.y;
  buf[tid] = s;
  __syncthreads();
  for (int off = 1; off < 256; off <<= 1) {
    int t1 = (tid >= off) ? buf[tid - off] : 0;
    __syncthreads();
    buf[tid] += t1;
    __syncthreads();
  }
  const int thr_excl = buf[tid] - s;
  if (idx * 2 < NCNT) {
    int e0 = sbase + thr_excl;
    ((int2*)coff)[idx] = make_int2(e0, e0 + c.x);   // exclusive offsets
    int p = idx * 2;
    if ((p & (BH_BLK - 1)) == 0) bucket_ptr[p >> 7] = e0;
    if (p + 1 == NCNT - 1) bucket_ptr[NBKT] = e0 + c.x + c.y;  // == N_EDGES
  }
}

// ---------------------------------------------------------------------------
// GEMM body for gemm1: out[M][64] = A[M][128] @ W[128][64], bf16 output rows.
// (R0 champion version — VALU fp32, 25.6KB LDS, 6 blocks/CU.)
template<int K>
__device__ __forceinline__ void gemm_body_bf(const float* __restrict__ A,
                                             const float* __restrict__ W,
                                             unsigned short* __restrict__ out,
                                             int M, int row0, int tid,
                                             float* sX, float* sW) {
  const int tx = tid & 15, ty = tid >> 4;
  const int q = tid & 7, r0 = tid >> 3;
  float acc[4][4] = {};

  for (int kb = 0; kb < K; kb += 32) {
    __syncthreads();
    if ((kb & 63) == 0) {
#pragma unroll
      for (int i = 0; i < 16; i++)
        sW[i * 256 + tid] = W[kb * 64 + i * 256 + tid];
    }
#pragma unroll
    for (int rr = 0; rr < 64; rr += 32) {
      int r = r0 + rr;
      int gr = row0 + r;
      float4 v = make_float4(0.f, 0.f, 0.f, 0.f);
      if (gr < M) v = *(const float4*)&A[(size_t)gr * K + kb + q * 4];
      *(float4*)&sX[r * 36 + q * 4] = v;
    }
    __syncthreads();

    const int kw = kb & 63;
#pragma unroll 4
    for (int k = 0; k < 32; k += 4) {
      float4 wv[4];
#pragma unroll
      for (int kk = 0; kk < 4; kk++)
        wv[kk] = *(const float4*)&sW[(kw + k + kk) * 64 + tx * 4];
#pragma unroll
      for (int r = 0; r < 4; r++) {
        float4 xv = *(const float4*)&sX[(ty * 4 + r) * 36 + k];
        const float xs[4] = {xv.x, xv.y, xv.z, xv.w};
#pragma unroll
        for (int kk = 0; kk < 4; kk++) {
          acc[r][0] += xs[kk] * wv[kk].x;
          acc[r][1] += xs[kk] * wv[kk].y;
          acc[r][2] += xs[kk] * wv[kk].z;
          acc[r][3] += xs[kk] * wv[kk].w;
        }
      }
    }
  }

#pragma unroll
  for (int r = 0; r < 4; r++) {
    int gr = row0 + ty * 4 + r;
    if (gr < M) {
      ushort4 u;
      u.x = f2bf(acc[r][0]); u.y = f2bf(acc[r][1]);
      u.z = f2bf(acc[r][2]); u.w = f2bf(acc[r][3]);
      *(ushort4*)&out[(size_t)gr * 64 + tx * 4] = u;
    }
  }
}

// ---------------------------------------------------------------------------
// dispatch 3: blocks [0,GGRID) = gemm1 (x@W1 -> h1 bf16); blocks [GGRID..)
// = bucket-sorted edge scatter (packed (src<<6)|dst_local). The ~20us
// scatter hides under the full 782-tile gemm1 (R11 pairing — do not split).
__global__ __launch_bounds__(256) void gemm1_bscatter(
    const float* __restrict__ x, const float* __restrict__ W1,
    unsigned short* __restrict__ h1, const int* __restrict__ src,
    const int* __restrict__ dst, const int* __restrict__ coff,
    unsigned int* __restrict__ ebuf) {
  __shared__ float sX[64 * 36];
  __shared__ float sW[64 * 64];
  const int tid = threadIdx.x;
  if (blockIdx.x < GGRID) {
    gemm_body_bf<N_FEAT>(x, W1, h1, N_NODES, blockIdx.x * 64, tid, sX, sW);
  } else {
    int* loff = (int*)sX;                     // 782 ints fit easily
    const int k = blockIdx.x - GGRID;
    for (int i = tid; i < NBKT; i += 256) loff[i] = coff[i * BH_BLK + k];
    __syncthreads();
    const int base = k * EPB;
    for (int j = tid; j < EPB; j += 256) {
      int e = base + j;
      int d = dst[e];
      int pos = atomicAdd(&loff[d >> 6], 1);
      ebuf[pos] = ((unsigned int)src[e] << 6) | (unsigned int)(d & 63);
    }
  }
}

// ---------------------------------------------------------------------------
// dispatch 4: per-bucket LDS CSR sort + layer-1 gather + relu + dot(w2fc)
// -> z[node]. 782 blocks x 1024 threads (16 waves x 4 nodes). Edges staged
// into LDS during the count pass -> ebuf read ONCE (was 3x).
__global__ __launch_bounds__(1024, 8) void gather_z_fused(
    const unsigned short* __restrict__ h1,
    const unsigned int* __restrict__ ebuf,
    const int* __restrict__ bucket_ptr,
    const float* __restrict__ w2fc,
    float* __restrict__ z) {
  __shared__ unsigned int eL[BKT_CAP];
  __shared__ int colL[BKT_CAP];
  __shared__ int lstart[64];
  __shared__ int lcur[64];
  __shared__ float sw[64];
  const int tid = threadIdx.x;
  const int b = blockIdx.x;
  const int p0 = bucket_ptr[b];
  int cnt = bucket_ptr[b + 1] - p0;
  if (cnt > BKT_CAP) cnt = BKT_CAP;                 // never triggers

  if (tid < 64) { lstart[tid] = 0; sw[tid] = w2fc[tid]; }
  __syncthreads();
  for (int i = tid; i < cnt; i += 1024) {           // stage + count
    unsigned int u = ebuf[p0 + i];
    eL[i] = u;
    atomicAdd(&lstart[u & 63], 1);
  }
  __syncthreads();
  if (tid < 64) {
    int v = lstart[tid], s = v;
#pragma unroll
    for (int off = 1; off < 64; off <<= 1) {
      int t = __shfl_up(s, off, 64);
      if (tid >= off) s += t;
    }
    lstart[tid] = s - v;
    lcur[tid] = s - v;
  }
  __syncthreads();
  for (int i = tid; i < cnt; i += 1024) {           // scatter from LDS
    unsigned int u = eL[i];
    int pos = atomicAdd(&lcur[u & 63], 1);
    colL[pos] = (int)(u >> 6);
  }
  __syncthreads();

  const int lane = tid & 63, w = tid >> 6;
  const int eo = lane >> 4, qfo = (lane & 15) << 2;
#pragma unroll
  for (int ni = 0; ni < 4; ni++) {
    const int r = ni * 16 + w;
    const int i1 = lcur[r];
    int i = lstart[r];
    float4 acc = make_float4(0.f, 0.f, 0.f, 0.f);
    for (; i + 16 <= i1; i += 16) {
      int s0 = colL[i + eo];
      int s1 = colL[i + 4 + eo];
      int s2 = colL[i + 8 + eo];
      int s3 = colL[i + 12 + eo];
      ushort4 u0 = *(const ushort4*)&h1[(size_t)s0 * 64 + qfo];
      ushort4 u1 = *(const ushort4*)&h1[(size_t)s1 * 64 + qfo];
      ushort4 u2 = *(const ushort4*)&h1[(size_t)s2 * 64 + qfo];
      ushort4 u3 = *(const ushort4*)&h1[(size_t)s3 * 64 + qfo];
      acc.x += (bf2f(u0.x) + bf2f(u1.x)) + (bf2f(u2.x) + bf2f(u3.x));
      acc.y += (bf2f(u0.y) + bf2f(u1.y)) + (bf2f(u2.y) + bf2f(u3.y));
      acc.z += (bf2f(u0.z) + bf2f(u1.z)) + (bf2f(u2.z) + bf2f(u3.z));
      acc.w += (bf2f(u0.w) + bf2f(u1.w)) + (bf2f(u2.w) + bf2f(u3.w));
    }
    for (; i + 4 <= i1; i += 4) {
      int s = colL[i + eo];
      ushort4 u = *(const ushort4*)&h1[(size_t)s * 64 + qfo];
      acc.x += bf2f(u.x); acc.y += bf2f(u.y);
      acc.z += bf2f(u.z); acc.w += bf2f(u.w);
    }
    if (eo < i1 - i) {
      int s = colL[i + eo];
      ushort4 u = *(const ushort4*)&h1[(size_t)s * 64 + qfo];
      acc.x += bf2f(u.x); acc.y += bf2f(u.y);
      acc.z += bf2f(u.z); acc.w += bf2f(u.w);
    }
#pragma unroll
    for (int m = 16; m <= 32; m <<= 1) {            // reduce over eo
      acc.x += __shfl_xor(acc.x, m, 64);
      acc.y += __shfl_xor(acc.y, m, 64);
      acc.z += __shfl_xor(acc.z, m, 64);
      acc.w += __shfl_xor(acc.w, m, 64);
    }
    float p = fmaxf(acc.x, 0.f) * sw[qfo] + fmaxf(acc.y, 0.f) * sw[qfo + 1] +
              fmaxf(acc.z, 0.f) * sw[qfo + 2] + fmaxf(acc.w, 0.f) * sw[qfo + 3];
#pragma unroll
    for (int m = 1; m <= 8; m <<= 1) p += __shfl_xor(p, m, 64);
    int node = b * 64 + r;
    if (lane == 0 && node < N_NODES) z[node] = p;
  }
}

// ---------------------------------------------------------------------------
// dispatch 5: per-graph sum over EDGES whose dst lies in the graph's node
// range of z[src] (layer-2 aggregation collapsed); /count; sigmoid.
__global__ __launch_bounds__(256) void graph_pool(const float* __restrict__ z,
                                                  const unsigned int* __restrict__ ebuf,
                                                  const int* __restrict__ bucket_ptr,
                                                  const int* __restrict__ batch,
                                                  float* __restrict__ out) {
  __shared__ float sacc[4];
  int g = blockIdx.x;
  int tid = threadIdx.x, lane = tid & 63, w = tid >> 6;

  int lo = 0, hi = N_NODES;
  while (lo < hi) { int mid = (lo + hi) >> 1; if (batch[mid] < g) lo = mid + 1; else hi = mid; }
  const int start = lo;
  hi = N_NODES;
  while (lo < hi) { int mid = (lo + hi) >> 1; if (batch[mid] < g + 1) lo = mid + 1; else hi = mid; }
  const int end = lo;

  float s = 0.f;
  if (end > start) {
    const int b0 = start >> 6, b1 = ((end - 1) >> 6) + 1;
    for (int b = b0; b < b1; b++) {
      const int q0 = bucket_ptr[b], q1 = bucket_ptr[b + 1];
      const int base = b << 6;
      for (int i = q0 + tid; i < q1; i += 256) {
        unsigned int u = ebuf[i];
        int d = base + (int)(u & 63);
        if (d >= start && d < end) s += z[u >> 6];
      }
    }
  }
#pragma unroll
  for (int off = 32; off; off >>= 1) s += __shfl_down(s, off, 64);
  if (lane == 0) sacc[w] = s;
  __syncthreads();
  if (tid == 0) {
    float v = sacc[0] + sacc[1] + sacc[2] + sacc[3];
    v /= fmaxf((float)(end - start), 1.f);
    out[g] = 1.f / (1.f + expf(-v));
  }
}

// ---------------------------------------------------------------------------
extern "C" void kernel_launch(void* const* d_in, const int* in_sizes, int n_in,
                              void* d_out, int out_size, void* d_ws, size_t ws_size,
                              hipStream_t stream) {
  const float* x     = (const float*)d_in[0];
  const int*   ei    = (const int*)d_in[1];   // [2, E]: src then dst
  const int*   batch = (const int*)d_in[2];
  const float* W1    = (const float*)d_in[3];
  const float* W2    = (const float*)d_in[4];
  const float* Wfc   = (const float*)d_in[5];
  float*       out   = (float*)d_out;

  const int* src = ei;
  const int* dst = ei + N_EDGES;

  // workspace layout (~11 MB, all disjoint)
  char* ws = (char*)d_ws;
  unsigned short* h1 = (unsigned short*)(ws);                  // [N,64] bf16
  float* z    = (float*)(ws + (size_t)N_NODES * DIM * 2);      // [N]
  float* w2fc = z + N_NODES;                                   // [64]
  int*   cnt  = (int*)(w2fc + 64);                             // [NCNT] raw
  int*   coff = cnt + NCNT;                                    // [NCNT] offsets
  unsigned int* ebuf = (unsigned int*)(coff + NCNT);           // [E]
  int*   bucket_ptr  = (int*)(ebuf + N_EDGES);                 // [NBKT+1]

  // CSR front half: bucket histogram (+w2fc) -> fused prefix scan
  bhist_w2fc<<<BH_BLK + 1, 256, 0, stream>>>(dst, cnt, W2, Wfc, w2fc);
  f_scan<<<P2_NBLK, 256, 0, stream>>>(cnt, coff, bucket_ptr);

  // gemm1 (h1 = bf16(x@W1)) || bucket-sorted edge scatter (R11 pairing)
  gemm1_bscatter<<<GGRID + BH_BLK, 256, 0, stream>>>(x, W1, h1, src, dst,
                                                     coff, ebuf);

  // per-bucket sort + layer-1 gather + relu + dot(W2@Wfc) -> z[N]
  gather_z_fused<<<NBKT, 1024, 0, stream>>>(h1, ebuf, bucket_ptr, w2fc, z);

  // per-graph edge-sum of z[src], mean, sigmoid
  graph_pool<<<N_GRAPHS, 256, 0, stream>>>(z, ebuf, bucket_ptr, batch, out);
}

// Round 5
// 145.666 us; speedup vs baseline: 1.4119x; 1.3607x over previous
//
#include <hip/hip_runtime.h>
#include <cmath>

#define N_NODES 50000
#define N_EDGES 800000
#define N_FEAT 128
#define DIM 64
#define N_GRAPHS 512
#define GGRID ((N_NODES + 63) / 64)         // 782 gemm1 tiles / buckets
#define NBKT GGRID                          // bucket = dst>>6
#define BH_BLK 256                          // edge-pass blocks (hist/scatter)
#define EPB (N_EDGES / BH_BLK)              // 3125 edges per edge-pass block
#define NCNT (NBKT * BH_BLK)                // 200192 count-matrix entries
#define P2_NBLK ((NCNT + 1023) / 1024)      // 196 scan blocks (1024 elems each)
#define BKT_CAP 2048                        // max bucket edges (mean 1024)

// bf16 storage helpers (RNE). Storage-only: all math in fp32.
__device__ __forceinline__ unsigned short f2bf(float f) {
  union { float f; unsigned int u; } v; v.f = f;
  return (unsigned short)((v.u + 0x7FFFu + ((v.u >> 16) & 1u)) >> 16);
}
__device__ __forceinline__ float bf2f(unsigned short u) {
  union { unsigned int u; float f; } v; v.u = (unsigned int)u << 16;
  return v.f;
}

// ---------------------------------------------------------------------------
// dispatch 1: blocks [0,256) bucket histogram of dst>>6 (cnt bucket-major:
// cnt[b*BH_BLK + k]); block 256 = w2fc = W2@Wfc precompute.
// BH_BLK=256 (was 128): edge passes were occupancy-starved at half the CUs.
__global__ __launch_bounds__(256) void bhist_w2fc(const int* __restrict__ dst,
                                                  int* __restrict__ cnt,
                                                  const float* __restrict__ W2,
                                                  const float* __restrict__ Wfc,
                                                  float* __restrict__ w2fc) {
  if (blockIdx.x == BH_BLK) {
    int k = threadIdx.x;
    if (k < 64) {
      float s = 0.f;
#pragma unroll 8
      for (int j = 0; j < 64; j++) s += W2[k * 64 + j] * Wfc[j];
      w2fc[k] = s;
    }
    return;
  }
  __shared__ int lh[NBKT];
  const int tid = threadIdx.x, k = blockIdx.x;
  for (int i = tid; i < NBKT; i += 256) lh[i] = 0;
  __syncthreads();
  const int base = k * EPB;
  for (int j = tid; j < EPB; j += 256)
    atomicAdd(&lh[dst[base + j] >> 6], 1);
  __syncthreads();
  for (int i = tid; i < NBKT; i += 256) cnt[i * BH_BLK + k] = lh[i];
}

// ---------------------------------------------------------------------------
// dispatch 2: per-1024-chunk RAW sums of cnt (196 blocks, int4-indexed).
// (Parallel 2-kernel scan restored — R4's fused serial-chain scan was 55us.)
__global__ __launch_bounds__(256) void f_psum(const int* __restrict__ cnt,
                                              int* __restrict__ partials) {
  __shared__ int ws[4];
  const int tid = threadIdx.x;
  const int4* c4 = (const int4*)cnt;
  int idx = blockIdx.x * 256 + tid;                 // int4 index
  int v = 0;
  if (idx * 4 < NCNT) { int4 c = c4[idx]; v = (c.x + c.y) + (c.z + c.w); }
#pragma unroll
  for (int off = 32; off; off >>= 1) v += __shfl_down(v, off, 64);
  int lane = tid & 63, w = tid >> 6;
  if (lane == 0) ws[w] = v;
  __syncthreads();
  if (tid == 0) partials[blockIdx.x] = ws[0] + ws[1] + ws[2] + ws[3];
}

// ---------------------------------------------------------------------------
// dispatch 3: block-local scan of 1024 cnt elems (int4 lanes) + redundant
// LDS scan of the 196 raw partials -> exclusive offsets coff + bucket_ptr.
__global__ __launch_bounds__(256) void f_sblocks(const int* __restrict__ cnt,
                                                 const int* __restrict__ partials,
                                                 int* __restrict__ coff,
                                                 int* __restrict__ bucket_ptr) {
  __shared__ int buf[256];
  __shared__ int pbuf[256];
  const int tid = threadIdx.x;
  const int4* c4 = (const int4*)cnt;
  const int idx = blockIdx.x * 256 + tid;
  int4 c = make_int4(0, 0, 0, 0);
  if (idx * 4 < NCNT) c = c4[idx];
  int s = (c.x + c.y) + (c.z + c.w);
  buf[tid] = s;
  pbuf[tid] = (tid < P2_NBLK) ? partials[tid] : 0;
  __syncthreads();
  for (int off = 1; off < 256; off <<= 1) {         // inclusive scans
    int t1 = (tid >= off) ? buf[tid - off] : 0;
    int t2 = (tid >= off) ? pbuf[tid - off] : 0;
    __syncthreads();
    buf[tid] += t1;
    pbuf[tid] += t2;
    __syncthreads();
  }
  const int thr_excl = buf[tid] - s;
  const int base = (blockIdx.x > 0) ? pbuf[blockIdx.x - 1] : 0;
  if (idx * 4 < NCNT) {
    int e0 = base + thr_excl;
    int4 o;
    o.x = e0; o.y = e0 + c.x; o.z = o.y + c.y; o.w = o.z + c.z;
    ((int4*)coff)[idx] = o;                         // exclusive offsets
    int p = idx * 4;
    if ((p & (BH_BLK - 1)) == 0) bucket_ptr[p >> 8] = e0;
    if (p + 3 == NCNT - 1) bucket_ptr[NBKT] = o.w + c.w;  // == N_EDGES
  }
}

// ---------------------------------------------------------------------------
// GEMM body for gemm1: out[M][64] = A[M][128] @ W[128][64], bf16 output rows.
// (R0 champion version — VALU fp32, 25.6KB LDS, 6 blocks/CU. MFMA variants
// measured neutral-to-worse; do not revisit without per-dispatch evidence.)
template<int K>
__device__ __forceinline__ void gemm_body_bf(const float* __restrict__ A,
                                             const float* __restrict__ W,
                                             unsigned short* __restrict__ out,
                                             int M, int row0, int tid,
                                             float* sX, float* sW) {
  const int tx = tid & 15, ty = tid >> 4;
  const int q = tid & 7, r0 = tid >> 3;
  float acc[4][4] = {};

  for (int kb = 0; kb < K; kb += 32) {
    __syncthreads();
    if ((kb & 63) == 0) {
#pragma unroll
      for (int i = 0; i < 16; i++)
        sW[i * 256 + tid] = W[kb * 64 + i * 256 + tid];
    }
#pragma unroll
    for (int rr = 0; rr < 64; rr += 32) {
      int r = r0 + rr;
      int gr = row0 + r;
      float4 v = make_float4(0.f, 0.f, 0.f, 0.f);
      if (gr < M) v = *(const float4*)&A[(size_t)gr * K + kb + q * 4];
      *(float4*)&sX[r * 36 + q * 4] = v;
    }
    __syncthreads();

    const int kw = kb & 63;
#pragma unroll 4
    for (int k = 0; k < 32; k += 4) {
      float4 wv[4];
#pragma unroll
      for (int kk = 0; kk < 4; kk++)
        wv[kk] = *(const float4*)&sW[(kw + k + kk) * 64 + tx * 4];
#pragma unroll
      for (int r = 0; r < 4; r++) {
        float4 xv = *(const float4*)&sX[(ty * 4 + r) * 36 + k];
        const float xs[4] = {xv.x, xv.y, xv.z, xv.w};
#pragma unroll
        for (int kk = 0; kk < 4; kk++) {
          acc[r][0] += xs[kk] * wv[kk].x;
          acc[r][1] += xs[kk] * wv[kk].y;
          acc[r][2] += xs[kk] * wv[kk].z;
          acc[r][3] += xs[kk] * wv[kk].w;
        }
      }
    }
  }

#pragma unroll
  for (int r = 0; r < 4; r++) {
    int gr = row0 + ty * 4 + r;
    if (gr < M) {
      ushort4 u;
      u.x = f2bf(acc[r][0]); u.y = f2bf(acc[r][1]);
      u.z = f2bf(acc[r][2]); u.w = f2bf(acc[r][3]);
      *(ushort4*)&out[(size_t)gr * 64 + tx * 4] = u;
    }
  }
}

// ---------------------------------------------------------------------------
// dispatch 4: blocks [0,GGRID) = gemm1 (x@W1 -> h1 bf16); blocks [GGRID..)
// = bucket-sorted edge scatter (packed (src<<6)|dst_local), now 256 blocks.
// Scatter hides under the full 782-tile gemm1 (R11 pairing — do not split).
__global__ __launch_bounds__(256) void gemm1_bscatter(
    const float* __restrict__ x, const float* __restrict__ W1,
    unsigned short* __restrict__ h1, const int* __restrict__ src,
    const int* __restrict__ dst, const int* __restrict__ coff,
    unsigned int* __restrict__ ebuf) {
  __shared__ float sX[64 * 36];
  __shared__ float sW[64 * 64];
  const int tid = threadIdx.x;
  if (blockIdx.x < GGRID) {
    gemm_body_bf<N_FEAT>(x, W1, h1, N_NODES, blockIdx.x * 64, tid, sX, sW);
  } else {
    int* loff = (int*)sX;                     // 782 ints fit easily
    const int k = blockIdx.x - GGRID;
    for (int i = tid; i < NBKT; i += 256) loff[i] = coff[i * BH_BLK + k];
    __syncthreads();
    const int base = k * EPB;
    for (int j = tid; j < EPB; j += 256) {
      int e = base + j;
      int d = dst[e];
      int pos = atomicAdd(&loff[d >> 6], 1);
      ebuf[pos] = ((unsigned int)src[e] << 6) | (unsigned int)(d & 63);
    }
  }
}

// ---------------------------------------------------------------------------
// dispatch 5: per-bucket LDS CSR sort + layer-1 gather + relu + dot(w2fc)
// -> z[node]. 782 blocks x 1024 threads (16 waves x 4 nodes). Edges staged
// into LDS during the count pass -> ebuf read ONCE (was 3x).
__global__ __launch_bounds__(1024, 8) void gather_z_fused(
    const unsigned short* __restrict__ h1,
    const unsigned int* __restrict__ ebuf,
    const int* __restrict__ bucket_ptr,
    const float* __restrict__ w2fc,
    float* __restrict__ z) {
  __shared__ unsigned int eL[BKT_CAP];
  __shared__ int colL[BKT_CAP];
  __shared__ int lstart[64];
  __shared__ int lcur[64];
  __shared__ float sw[64];
  const int tid = threadIdx.x;
  const int b = blockIdx.x;
  const int p0 = bucket_ptr[b];
  int cnt = bucket_ptr[b + 1] - p0;
  if (cnt > BKT_CAP) cnt = BKT_CAP;                 // never triggers

  if (tid < 64) { lstart[tid] = 0; sw[tid] = w2fc[tid]; }
  __syncthreads();
  for (int i = tid; i < cnt; i += 1024) {           // stage + count
    unsigned int u = ebuf[p0 + i];
    eL[i] = u;
    atomicAdd(&lstart[u & 63], 1);
  }
  __syncthreads();
  if (tid < 64) {
    int v = lstart[tid], s = v;
#pragma unroll
    for (int off = 1; off < 64; off <<= 1) {
      int t = __shfl_up(s, off, 64);
      if (tid >= off) s += t;
    }
    lstart[tid] = s - v;
    lcur[tid] = s - v;
  }
  __syncthreads();
  for (int i = tid; i < cnt; i += 1024) {           // scatter from LDS
    unsigned int u = eL[i];
    int pos = atomicAdd(&lcur[u & 63], 1);
    colL[pos] = (int)(u >> 6);
  }
  __syncthreads();

  const int lane = tid & 63, w = tid >> 6;
  const int eo = lane >> 4, qfo = (lane & 15) << 2;
#pragma unroll
  for (int ni = 0; ni < 4; ni++) {
    const int r = ni * 16 + w;
    const int i1 = lcur[r];
    int i = lstart[r];
    float4 acc = make_float4(0.f, 0.f, 0.f, 0.f);
    for (; i + 16 <= i1; i += 16) {
      int s0 = colL[i + eo];
      int s1 = colL[i + 4 + eo];
      int s2 = colL[i + 8 + eo];
      int s3 = colL[i + 12 + eo];
      ushort4 u0 = *(const ushort4*)&h1[(size_t)s0 * 64 + qfo];
      ushort4 u1 = *(const ushort4*)&h1[(size_t)s1 * 64 + qfo];
      ushort4 u2 = *(const ushort4*)&h1[(size_t)s2 * 64 + qfo];
      ushort4 u3 = *(const ushort4*)&h1[(size_t)s3 * 64 + qfo];
      acc.x += (bf2f(u0.x) + bf2f(u1.x)) + (bf2f(u2.x) + bf2f(u3.x));
      acc.y += (bf2f(u0.y) + bf2f(u1.y)) + (bf2f(u2.y) + bf2f(u3.y));
      acc.z += (bf2f(u0.z) + bf2f(u1.z)) + (bf2f(u2.z) + bf2f(u3.z));
      acc.w += (bf2f(u0.w) + bf2f(u1.w)) + (bf2f(u2.w) + bf2f(u3.w));
    }
    for (; i + 4 <= i1; i += 4) {
      int s = colL[i + eo];
      ushort4 u = *(const ushort4*)&h1[(size_t)s * 64 + qfo];
      acc.x += bf2f(u.x); acc.y += bf2f(u.y);
      acc.z += bf2f(u.z); acc.w += bf2f(u.w);
    }
    if (eo < i1 - i) {
      int s = colL[i + eo];
      ushort4 u = *(const ushort4*)&h1[(size_t)s * 64 + qfo];
      acc.x += bf2f(u.x); acc.y += bf2f(u.y);
      acc.z += bf2f(u.z); acc.w += bf2f(u.w);
    }
#pragma unroll
    for (int m = 16; m <= 32; m <<= 1) {            // reduce over eo
      acc.x += __shfl_xor(acc.x, m, 64);
      acc.y += __shfl_xor(acc.y, m, 64);
      acc.z += __shfl_xor(acc.z, m, 64);
      acc.w += __shfl_xor(acc.w, m, 64);
    }
    float p = fmaxf(acc.x, 0.f) * sw[qfo] + fmaxf(acc.y, 0.f) * sw[qfo + 1] +
              fmaxf(acc.z, 0.f) * sw[qfo + 2] + fmaxf(acc.w, 0.f) * sw[qfo + 3];
#pragma unroll
    for (int m = 1; m <= 8; m <<= 1) p += __shfl_xor(p, m, 64);
    int node = b * 64 + r;
    if (lane == 0 && node < N_NODES) z[node] = p;
  }
}

// ---------------------------------------------------------------------------
// dispatch 6: per-graph sum over EDGES whose dst lies in the graph's node
// range of z[src] (layer-2 aggregation collapsed); /count; sigmoid.
__global__ __launch_bounds__(256) void graph_pool(const float* __restrict__ z,
                                                  const unsigned int* __restrict__ ebuf,
                                                  const int* __restrict__ bucket_ptr,
                                                  const int* __restrict__ batch,
                                                  float* __restrict__ out) {
  __shared__ float sacc[4];
  int g = blockIdx.x;
  int tid = threadIdx.x, lane = tid & 63, w = tid >> 6;

  int lo = 0, hi = N_NODES;
  while (lo < hi) { int mid = (lo + hi) >> 1; if (batch[mid] < g) lo = mid + 1; else hi = mid; }
  const int start = lo;
  hi = N_NODES;
  while (lo < hi) { int mid = (lo + hi) >> 1; if (batch[mid] < g + 1) lo = mid + 1; else hi = mid; }
  const int end = lo;

  float s = 0.f;
  if (end > start) {
    const int b0 = start >> 6, b1 = ((end - 1) >> 6) + 1;
    for (int b = b0; b < b1; b++) {
      const int q0 = bucket_ptr[b], q1 = bucket_ptr[b + 1];
      const int base = b << 6;
      for (int i = q0 + tid; i < q1; i += 256) {
        unsigned int u = ebuf[i];
        int d = base + (int)(u & 63);
        if (d >= start && d < end) s += z[u >> 6];
      }
    }
  }
#pragma unroll
  for (int off = 32; off; off >>= 1) s += __shfl_down(s, off, 64);
  if (lane == 0) sacc[w] = s;
  __syncthreads();
  if (tid == 0) {
    float v = sacc[0] + sacc[1] + sacc[2] + sacc[3];
    v /= fmaxf((float)(end - start), 1.f);
    out[g] = 1.f / (1.f + expf(-v));
  }
}

// ---------------------------------------------------------------------------
extern "C" void kernel_launch(void* const* d_in, const int* in_sizes, int n_in,
                              void* d_out, int out_size, void* d_ws, size_t ws_size,
                              hipStream_t stream) {
  const float* x     = (const float*)d_in[0];
  const int*   ei    = (const int*)d_in[1];   // [2, E]: src then dst
  const int*   batch = (const int*)d_in[2];
  const float* W1    = (const float*)d_in[3];
  const float* W2    = (const float*)d_in[4];
  const float* Wfc   = (const float*)d_in[5];
  float*       out   = (float*)d_out;

  const int* src = ei;
  const int* dst = ei + N_EDGES;

  // workspace layout (~12 MB, all disjoint)
  char* ws = (char*)d_ws;
  unsigned short* h1 = (unsigned short*)(ws);                  // [N,64] bf16
  float* z    = (float*)(ws + (size_t)N_NODES * DIM * 2);      // [N]
  float* w2fc = z + N_NODES;                                   // [64]
  int*   cnt  = (int*)(w2fc + 64);                             // [NCNT] raw
  int*   partials = cnt + NCNT;                                // [256] (196 used)
  int*   coff = partials + 256;                                // [NCNT] offsets
  unsigned int* ebuf = (unsigned int*)(coff + NCNT);           // [E]
  int*   bucket_ptr  = (int*)(ebuf + N_EDGES);                 // [NBKT+1]

  // CSR front half: bucket histogram (+w2fc) -> raw sums -> fused scan
  bhist_w2fc<<<BH_BLK + 1, 256, 0, stream>>>(dst, cnt, W2, Wfc, w2fc);
  f_psum<<<P2_NBLK, 256, 0, stream>>>(cnt, partials);
  f_sblocks<<<P2_NBLK, 256, 0, stream>>>(cnt, partials, coff, bucket_ptr);

  // gemm1 (h1 = bf16(x@W1)) || bucket-sorted edge scatter (R11 pairing)
  gemm1_bscatter<<<GGRID + BH_BLK, 256, 0, stream>>>(x, W1, h1, src, dst,
                                                     coff, ebuf);

  // per-bucket sort + layer-1 gather + relu + dot(W2@Wfc) -> z[N]
  gather_z_fused<<<NBKT, 1024, 0, stream>>>(h1, ebuf, bucket_ptr, w2fc, z);

  // per-graph edge-sum of z[src], mean, sigmoid
  graph_pool<<<N_GRAPHS, 256, 0, stream>>>(z, ebuf, bucket_ptr, batch, out);
}

// Round 6
// 138.563 us; speedup vs baseline: 1.4843x; 1.0513x over previous
//
#include <hip/hip_runtime.h>
#include <cmath>

#define N_NODES 50000
#define N_EDGES 800000
#define N_FEAT 128
#define DIM 64
#define N_GRAPHS 512
#define GGRID ((N_NODES + 63) / 64)         // 782 gemm1 tiles / buckets
#define NBKT GGRID                          // bucket = dst>>6
#define BH_BLK 256                          // scatter blocks (edge pass)
#define EPB (N_EDGES / BH_BLK)              // 3125 edges per scatter block
#define BKT_CAP 2048                        // fixed slot region per bucket

// bf16 storage helpers (RNE). Storage-only: all math in fp32.
__device__ __forceinline__ unsigned short f2bf(float f) {
  union { float f; unsigned int u; } v; v.f = f;
  return (unsigned short)((v.u + 0x7FFFu + ((v.u >> 16) & 1u)) >> 16);
}
__device__ __forceinline__ float bf2f(unsigned short u) {
  union { unsigned int u; float f; } v; v.u = (unsigned int)u << 16;
  return v.f;
}

// ---------------------------------------------------------------------------
// GEMM body for gemm1: out[M][64] = A[M][128] @ W[128][64], bf16 output rows.
// (R0 champion version — VALU fp32, 25.6KB LDS, 6 blocks/CU. MFMA variants
// measured neutral-to-worse; do not revisit without per-dispatch evidence.)
template<int K>
__device__ __forceinline__ void gemm_body_bf(const float* __restrict__ A,
                                             const float* __restrict__ W,
                                             unsigned short* __restrict__ out,
                                             int M, int row0, int tid,
                                             float* sX, float* sW) {
  const int tx = tid & 15, ty = tid >> 4;
  const int q = tid & 7, r0 = tid >> 3;
  float acc[4][4] = {};

  for (int kb = 0; kb < K; kb += 32) {
    __syncthreads();
    if ((kb & 63) == 0) {
#pragma unroll
      for (int i = 0; i < 16; i++)
        sW[i * 256 + tid] = W[kb * 64 + i * 256 + tid];
    }
#pragma unroll
    for (int rr = 0; rr < 64; rr += 32) {
      int r = r0 + rr;
      int gr = row0 + r;
      float4 v = make_float4(0.f, 0.f, 0.f, 0.f);
      if (gr < M) v = *(const float4*)&A[(size_t)gr * K + kb + q * 4];
      *(float4*)&sX[r * 36 + q * 4] = v;
    }
    __syncthreads();

    const int kw = kb & 63;
#pragma unroll 4
    for (int k = 0; k < 32; k += 4) {
      float4 wv[4];
#pragma unroll
      for (int kk = 0; kk < 4; kk++)
        wv[kk] = *(const float4*)&sW[(kw + k + kk) * 64 + tx * 4];
#pragma unroll
      for (int r = 0; r < 4; r++) {
        float4 xv = *(const float4*)&sX[(ty * 4 + r) * 36 + k];
        const float xs[4] = {xv.x, xv.y, xv.z, xv.w};
#pragma unroll
        for (int kk = 0; kk < 4; kk++) {
          acc[r][0] += xs[kk] * wv[kk].x;
          acc[r][1] += xs[kk] * wv[kk].y;
          acc[r][2] += xs[kk] * wv[kk].z;
          acc[r][3] += xs[kk] * wv[kk].w;
        }
      }
    }
  }

#pragma unroll
  for (int r = 0; r < 4; r++) {
    int gr = row0 + ty * 4 + r;
    if (gr < M) {
      ushort4 u;
      u.x = f2bf(acc[r][0]); u.y = f2bf(acc[r][1]);
      u.z = f2bf(acc[r][2]); u.w = f2bf(acc[r][3]);
      *(ushort4*)&out[(size_t)gr * 64 + tx * 4] = u;
    }
  }
}

// ---------------------------------------------------------------------------
// dispatch 1 (fused front-end): the entire former D1-D4 chain in ONE kernel.
//   blocks [0,BH_BLK):  slotted bucket scatter — LDS histogram of dst>>6,
//                       chunk reservation via global atomicAdd on gcur[782]
//                       (slot region b*BKT_CAP fixed -> no prefix scan, no
//                       cnt/coff matrix, no separate hist dispatch), then
//                       LDS-cursor scatter of packed (src<<6)|dst_local.
//   block  BH_BLK:      w2fc = W2@Wfc precompute.
//   blocks (BH_BLK..]:  gemm1 (x@W1 -> h1 bf16), 782 tiles; scatter and
//                       reservation atomics hide under it (R11 pairing).
// Within-bucket edge order is nondeterministic (atomic arrival) — only
// permutes fp-add order per node; R3 measured bit-identical absmax.
__global__ __launch_bounds__(256) void fused_main(
    const float* __restrict__ x, const float* __restrict__ W1,
    unsigned short* __restrict__ h1, const int* __restrict__ src,
    const int* __restrict__ dst, int* __restrict__ gcur,
    unsigned int* __restrict__ ebuf, const float* __restrict__ W2,
    const float* __restrict__ Wfc, float* __restrict__ w2fc) {
  __shared__ float sX[64 * 36];
  __shared__ float sW[64 * 64];
  const int tid = threadIdx.x;
  if (blockIdx.x < BH_BLK) {
    int* lh = (int*)sX;                     // [NBKT] block-local counts
    int* lbase = (int*)sW;                  // [NBKT] reserved global slots
    int* lcur = lbase + NBKT;               // [NBKT] block-local cursors
    for (int i = tid; i < NBKT; i += 256) { lh[i] = 0; lcur[i] = 0; }
    __syncthreads();
    const int base = blockIdx.x * EPB;
    for (int j = tid; j < EPB; j += 256)
      atomicAdd(&lh[dst[base + j] >> 6], 1);
    __syncthreads();
    for (int i = tid; i < NBKT; i += 256) {
      int n = lh[i];
      lbase[i] = (n > 0) ? i * BKT_CAP + atomicAdd(&gcur[i], n) : 0;
    }
    __syncthreads();
    for (int j = tid; j < EPB; j += 256) {
      int e = base + j;
      int d = dst[e];
      int b = d >> 6;
      int pos = atomicAdd(&lcur[b], 1);
      unsigned int gpos = (unsigned int)(lbase[b] + pos);
      if (gpos < (unsigned int)((b + 1) * BKT_CAP))   // overflow guard
        ebuf[gpos] = ((unsigned int)src[e] << 6) | (unsigned int)(d & 63);
    }
  } else if (blockIdx.x == BH_BLK) {
    int k = tid;
    if (k < 64) {
      float s = 0.f;
#pragma unroll 8
      for (int j = 0; j < 64; j++) s += W2[k * 64 + j] * Wfc[j];
      w2fc[k] = s;
    }
  } else {
    gemm_body_bf<N_FEAT>(x, W1, h1, N_NODES, (blockIdx.x - BH_BLK - 1) * 64,
                         tid, sX, sW);
  }
}

// ---------------------------------------------------------------------------
// dispatch 2: per-bucket LDS CSR sort + layer-1 gather + relu + dot(w2fc)
// -> z[node]. 782 blocks x 1024 threads (16 waves x 4 nodes). Bucket region
// is the fixed slot range [b*BKT_CAP, b*BKT_CAP + gcur[b]); edges staged
// into LDS during the count pass -> ebuf read ONCE.
__global__ __launch_bounds__(1024, 8) void gather_z_fused(
    const unsigned short* __restrict__ h1,
    const unsigned int* __restrict__ ebuf,
    const int* __restrict__ gcur,
    const float* __restrict__ w2fc,
    float* __restrict__ z) {
  __shared__ unsigned int eL[BKT_CAP];
  __shared__ int colL[BKT_CAP];
  __shared__ int lstart[64];
  __shared__ int lcur[64];
  __shared__ float sw[64];
  const int tid = threadIdx.x;
  const int b = blockIdx.x;
  const int p0 = b * BKT_CAP;
  int cnt = gcur[b];
  if (cnt > BKT_CAP) cnt = BKT_CAP;                 // never triggers

  if (tid < 64) { lstart[tid] = 0; sw[tid] = w2fc[tid]; }
  __syncthreads();
  for (int i = tid; i < cnt; i += 1024) {           // stage + count
    unsigned int u = ebuf[p0 + i];
    eL[i] = u;
    atomicAdd(&lstart[u & 63], 1);
  }
  __syncthreads();
  if (tid < 64) {
    int v = lstart[tid], s = v;
#pragma unroll
    for (int off = 1; off < 64; off <<= 1) {
      int t = __shfl_up(s, off, 64);
      if (tid >= off) s += t;
    }
    lstart[tid] = s - v;
    lcur[tid] = s - v;
  }
  __syncthreads();
  for (int i = tid; i < cnt; i += 1024) {           // scatter from LDS
    unsigned int u = eL[i];
    int pos = atomicAdd(&lcur[u & 63], 1);
    colL[pos] = (int)(u >> 6);
  }
  __syncthreads();

  const int lane = tid & 63, w = tid >> 6;
  const int eo = lane >> 4, qfo = (lane & 15) << 2;
#pragma unroll
  for (int ni = 0; ni < 4; ni++) {
    const int r = ni * 16 + w;
    const int i1 = lcur[r];
    int i = lstart[r];
    float4 acc = make_float4(0.f, 0.f, 0.f, 0.f);
    for (; i + 16 <= i1; i += 16) {
      int s0 = colL[i + eo];
      int s1 = colL[i + 4 + eo];
      int s2 = colL[i + 8 + eo];
      int s3 = colL[i + 12 + eo];
      ushort4 u0 = *(const ushort4*)&h1[(size_t)s0 * 64 + qfo];
      ushort4 u1 = *(const ushort4*)&h1[(size_t)s1 * 64 + qfo];
      ushort4 u2 = *(const ushort4*)&h1[(size_t)s2 * 64 + qfo];
      ushort4 u3 = *(const ushort4*)&h1[(size_t)s3 * 64 + qfo];
      acc.x += (bf2f(u0.x) + bf2f(u1.x)) + (bf2f(u2.x) + bf2f(u3.x));
      acc.y += (bf2f(u0.y) + bf2f(u1.y)) + (bf2f(u2.y) + bf2f(u3.y));
      acc.z += (bf2f(u0.z) + bf2f(u1.z)) + (bf2f(u2.z) + bf2f(u3.z));
      acc.w += (bf2f(u0.w) + bf2f(u1.w)) + (bf2f(u2.w) + bf2f(u3.w));
    }
    for (; i + 4 <= i1; i += 4) {
      int s = colL[i + eo];
      ushort4 u = *(const ushort4*)&h1[(size_t)s * 64 + qfo];
      acc.x += bf2f(u.x); acc.y += bf2f(u.y);
      acc.z += bf2f(u.z); acc.w += bf2f(u.w);
    }
    if (eo < i1 - i) {
      int s = colL[i + eo];
      ushort4 u = *(const ushort4*)&h1[(size_t)s * 64 + qfo];
      acc.x += bf2f(u.x); acc.y += bf2f(u.y);
      acc.z += bf2f(u.z); acc.w += bf2f(u.w);
    }
#pragma unroll
    for (int m = 16; m <= 32; m <<= 1) {            // reduce over eo
      acc.x += __shfl_xor(acc.x, m, 64);
      acc.y += __shfl_xor(acc.y, m, 64);
      acc.z += __shfl_xor(acc.z, m, 64);
      acc.w += __shfl_xor(acc.w, m, 64);
    }
    float p = fmaxf(acc.x, 0.f) * sw[qfo] + fmaxf(acc.y, 0.f) * sw[qfo + 1] +
              fmaxf(acc.z, 0.f) * sw[qfo + 2] + fmaxf(acc.w, 0.f) * sw[qfo + 3];
#pragma unroll
    for (int m = 1; m <= 8; m <<= 1) p += __shfl_xor(p, m, 64);
    int node = b * 64 + r;
    if (lane == 0 && node < N_NODES) z[node] = p;
  }
}

// ---------------------------------------------------------------------------
// dispatch 3: per-graph sum over EDGES whose dst lies in the graph's node
// range of z[src] (layer-2 aggregation collapsed); /count; sigmoid.
__global__ __launch_bounds__(256) void graph_pool(const float* __restrict__ z,
                                                  const unsigned int* __restrict__ ebuf,
                                                  const int* __restrict__ gcur,
                                                  const int* __restrict__ batch,
                                                  float* __restrict__ out) {
  __shared__ float sacc[4];
  int g = blockIdx.x;
  int tid = threadIdx.x, lane = tid & 63, w = tid >> 6;

  int lo = 0, hi = N_NODES;
  while (lo < hi) { int mid = (lo + hi) >> 1; if (batch[mid] < g) lo = mid + 1; else hi = mid; }
  const int start = lo;
  hi = N_NODES;
  while (lo < hi) { int mid = (lo + hi) >> 1; if (batch[mid] < g + 1) lo = mid + 1; else hi = mid; }
  const int end = lo;

  float s = 0.f;
  if (end > start) {
    const int b0 = start >> 6, b1 = ((end - 1) >> 6) + 1;
    for (int b = b0; b < b1; b++) {
      int bc = gcur[b];
      if (bc > BKT_CAP) bc = BKT_CAP;
      const int q0 = b * BKT_CAP, q1 = q0 + bc;
      const int base = b << 6;
      for (int i = q0 + tid; i < q1; i += 256) {
        unsigned int u = ebuf[i];
        int d = base + (int)(u & 63);
        if (d >= start && d < end) s += z[u >> 6];
      }
    }
  }
#pragma unroll
  for (int off = 32; off; off >>= 1) s += __shfl_down(s, off, 64);
  if (lane == 0) sacc[w] = s;
  __syncthreads();
  if (tid == 0) {
    float v = sacc[0] + sacc[1] + sacc[2] + sacc[3];
    v /= fmaxf((float)(end - start), 1.f);
    out[g] = 1.f / (1.f + expf(-v));
  }
}

// ---------------------------------------------------------------------------
extern "C" void kernel_launch(void* const* d_in, const int* in_sizes, int n_in,
                              void* d_out, int out_size, void* d_ws, size_t ws_size,
                              hipStream_t stream) {
  const float* x     = (const float*)d_in[0];
  const int*   ei    = (const int*)d_in[1];   // [2, E]: src then dst
  const int*   batch = (const int*)d_in[2];
  const float* W1    = (const float*)d_in[3];
  const float* W2    = (const float*)d_in[4];
  const float* Wfc   = (const float*)d_in[5];
  float*       out   = (float*)d_out;

  const int* src = ei;
  const int* dst = ei + N_EDGES;

  // workspace layout (~13 MB, all disjoint, 16B-aligned sections)
  char* ws = (char*)d_ws;
  unsigned short* h1 = (unsigned short*)(ws);                  // [N,64] bf16
  float* z    = (float*)(ws + (size_t)N_NODES * DIM * 2);      // [N]
  float* w2fc = z + N_NODES;                                   // [64]
  int*   gcur = (int*)(w2fc + 64);                             // [NBKT] (pad 800)
  unsigned int* ebuf = (unsigned int*)(gcur + 800);            // [NBKT*BKT_CAP]

  // zero bucket cursors, then the whole former D1-D4 chain in one kernel:
  // slotted scatter (blocks 0..255) || w2fc || gemm1 (h1 = bf16(x@W1))
  hipMemsetAsync(gcur, 0, NBKT * sizeof(int), stream);
  fused_main<<<BH_BLK + 1 + GGRID, 256, 0, stream>>>(x, W1, h1, src, dst,
                                                     gcur, ebuf, W2, Wfc, w2fc);

  // per-bucket sort + layer-1 gather + relu + dot(W2@Wfc) -> z[N]
  gather_z_fused<<<NBKT, 1024, 0, stream>>>(h1, ebuf, gcur, w2fc, z);

  // per-graph edge-sum of z[src], mean, sigmoid
  graph_pool<<<N_GRAPHS, 256, 0, stream>>>(z, ebuf, gcur, batch, out);
}